// Round 8
// baseline (172.913 us; speedup 1.0000x reference)
//
#include <hip/hip_runtime.h>
#include <math.h>

#define B_ 64
#define S_ 512
#define N_ 24
#define H_ 768
#define C_ 6
#define CHUNKS2 32
#define TOK (S_ / CHUNKS2)  // 16 tokens per block

// Stage 1: segmented column sum. Thread = one float4 column (192 threads cover
// H=768). Copy-kernel-like: tiny VGPR, no W, no cross-lane, depth-2 pipelined
// loads, uniform branches. 2048 blocks x 192 thr -> 8 blocks/CU, 24 waves/CU.
__global__ __launch_bounds__(192) void seg_sum_kernel(
    const float* __restrict__ lhs, const int* __restrict__ st,
    float* __restrict__ segsum) {
  __shared__ int lst[N_];
  const int tid = threadIdx.x;  // column float4 index, 0..191
  const int b = blockIdx.x / CHUNKS2;
  const int chunk = blockIdx.x % CHUNKS2;
  if (tid < N_) lst[tid] = st[b * N_ + tid];
  __syncthreads();
  const int last = lst[N_ - 1];
  const int s0 = chunk * TOK;
  if (s0 > last) return;  // uniform: chunk entirely past last boundary
  const int s_stop = min(s0 + TOK, last + 1);

  int j = 0;  // segment of token s0: first j with lst[j] >= s0 (uniform)
  while (lst[j] < s0) ++j;

  const float4* X4 = (const float4*)lhs + ((size_t)b * S_ + s0) * (H_ / 4) + tid;
  float4 acc = make_float4(0.f, 0.f, 0.f, 0.f);
  bool dirty = false;
  float4 x = X4[0];
  for (int s = s0; s < s_stop; ++s) {
    float4 xn = make_float4(0.f, 0.f, 0.f, 0.f);
    if (s + 1 < s_stop) xn = X4[(size_t)(s - s0 + 1) * (H_ / 4)];  // prefetch
    acc.x += x.x; acc.y += x.y; acc.z += x.z; acc.w += x.w;
    dirty = true;
    if (s == lst[j]) {  // uniform: flush completed segment
      float* dst = segsum + ((size_t)(b * N_ + j) * (H_ / 4) + tid) * 4;
      atomicAdd(dst + 0, acc.x); atomicAdd(dst + 1, acc.y);
      atomicAdd(dst + 2, acc.z); atomicAdd(dst + 3, acc.w);
      acc = make_float4(0.f, 0.f, 0.f, 0.f);
      dirty = false;
      ++j;
    }
    x = xn;
  }
  if (dirty) {  // partial segment at chunk end
    float* dst = segsum + ((size_t)(b * N_ + j) * (H_ / 4) + tid) * 4;
    atomicAdd(dst + 0, acc.x); atomicAdd(dst + 1, acc.y);
    atomicAdd(dst + 2, acc.z); atomicAdd(dst + 3, acc.w);
  }
}

// VALU-pipe cross-lane add via DPP (immediate ctrl via template) — verified R7.
template <int CTRL>
__device__ __forceinline__ float dpp_add(float v) {
  int x = __builtin_amdgcn_update_dpp(0, __float_as_int(v), CTRL, 0xF, 0xF, true);
  return v + __int_as_float(x);
}
__device__ __forceinline__ float wave_sum(float v) {
  v = dpp_add<0xB1>(v);
  v = dpp_add<0x4E>(v);
  v = dpp_add<0x141>(v);
  v = dpp_add<0x140>(v);
  v += __shfl_xor(v, 16, 64);
  v += __shfl_xor(v, 32, 64);
  return v;
}

// Stage 2: project seg_sum (4.7 MB) to C=6, mean+bias+sigmoid+override.
// One wave per (b,j): 1536 blocks x 64 threads.
__global__ __launch_bounds__(64) void proj_out_kernel(
    const float* __restrict__ segsum, const int* __restrict__ st,
    const float* __restrict__ W, const float* __restrict__ bias,
    float* __restrict__ out) {
  const int lane = threadIdx.x;
  const int bj = blockIdx.x;
  const int b = bj / N_;
  const int j = bj % N_;
  const int end = st[b * N_ + j];
  const int prev = (j == 0) ? -1 : st[b * N_ + j - 1];

  const float4* X4 = (const float4*)segsum + (size_t)bj * (H_ / 4);
  const float4* W4 = (const float4*)W;
  float4 x0 = X4[lane], x1 = X4[64 + lane], x2 = X4[128 + lane];
  float y[C_];
#pragma unroll
  for (int c = 0; c < C_; ++c) {
    float4 w0 = W4[c * (H_ / 4) + lane];
    float4 w1 = W4[c * (H_ / 4) + 64 + lane];
    float4 w2 = W4[c * (H_ / 4) + 128 + lane];
    y[c] = x0.x * w0.x + x0.y * w0.y + x0.z * w0.z + x0.w * w0.w +
           x1.x * w1.x + x1.y * w1.y + x1.z * w1.z + x1.w * w1.w +
           x2.x * w2.x + x2.y * w2.y + x2.z * w2.z + x2.w * w2.w;
  }
#pragma unroll
  for (int c = 0; c < C_; ++c) y[c] = wave_sum(y[c]);

  if (lane < C_) {
    const int c = lane;
    float v = y[0];
    v = (c == 1) ? y[1] : v;
    v = (c == 2) ? y[2] : v;
    v = (c == 3) ? y[3] : v;
    v = (c == 4) ? y[4] : v;
    v = (c == 5) ? y[5] : v;
    float logit = v / (float)(end - prev) + bias[c];
    float p = 1.0f / (1.0f + expf(-logit));
    if (end > 500) {
      float cl = (c < 3) ? 0.1f : (c == 3 ? 0.3f : (c == 4 ? 0.8f : 0.01f));
      float cm = (c < 3) ? 0.1f : (c == 3 ? 0.8f : (c == 4 ? 0.3f : 0.01f));
      p = (j == N_ - 1) ? cl : cm;
    }
    out[bj * C_ + c] = p;
  }
}

extern "C" void kernel_launch(void* const* d_in, const int* in_sizes, int n_in,
                              void* d_out, int out_size, void* d_ws, size_t ws_size,
                              hipStream_t stream) {
  const float* lhs  = (const float*)d_in[0];  // [B,S,H] fp32
  const int*   st   = (const int*)d_in[1];    // [B,N] int32
  const float* W    = (const float*)d_in[2];  // [C,H] fp32
  const float* bias = (const float*)d_in[3];  // [C] fp32
  float* segsum = (float*)d_ws;               // [B,N,H] fp32 (4.7 MB)

  hipMemsetAsync(d_ws, 0, (size_t)B_ * N_ * H_ * sizeof(float), stream);
  seg_sum_kernel<<<B_ * CHUNKS2, 192, 0, stream>>>(lhs, st, segsum);
  proj_out_kernel<<<B_ * N_, 64, 0, stream>>>(segsum, st, W, bias, (float*)d_out);
}